// Round 1
// baseline (502.081 us; speedup 1.0000x reference)
//
#include <hip/hip_runtime.h>
#include <math.h>

#define N_  8
#define C_  19
#define H_  512
#define W_  1024
#define HW_ (H_ * W_)          // 524288
#define NPIX (N_ * HW_)        // 4194304
#define IGNORE_IDX 255

// Workspace layout (zeroed at start of every launch):
//   [0,   608)  int    hist[N_][C_]      (152 ints)
//   [608, 612)  int    valid_count
//   [616, 624)  double loss_sum
#define WS_HIST_OFF   0
#define WS_VALID_OFF  608
#define WS_LOSS_OFF   616
#define WS_ZERO_BYTES 1024

// ---------------------------------------------------------------------------
// Kernel 1: per-sample class histogram (in-range targets) + valid-pixel count
// ---------------------------------------------------------------------------
__global__ __launch_bounds__(256) void hist_kernel(
    const int* __restrict__ tgt, int* __restrict__ hist, int* __restrict__ valid_cnt) {
  __shared__ int lhist[N_ * C_];
  __shared__ int lvalid;
  const int tid = threadIdx.x;
  for (int i = tid; i < N_ * C_; i += blockDim.x) lhist[i] = 0;
  if (tid == 0) lvalid = 0;
  __syncthreads();

  int lv = 0;
  const int total4 = NPIX / 4;
  for (int i = blockIdx.x * blockDim.x + tid; i < total4;
       i += gridDim.x * blockDim.x) {
    const int4 t4 = reinterpret_cast<const int4*>(tgt)[i];
    const int n = (i * 4) / HW_;   // HW_ % 4 == 0 -> all 4 elems same sample
    const int tv[4] = {t4.x, t4.y, t4.z, t4.w};
#pragma unroll
    for (int j = 0; j < 4; ++j) {
      if (tv[j] != IGNORE_IDX) ++lv;
      if (tv[j] >= 0 && tv[j] < C_) atomicAdd(&lhist[n * C_ + tv[j]], 1);
    }
  }
  atomicAdd(&lvalid, lv);
  __syncthreads();

  for (int i = tid; i < N_ * C_; i += blockDim.x)
    if (lhist[i] != 0) atomicAdd(&hist[i], lhist[i]);
  if (tid == 0) atomicAdd(valid_cnt, lvalid);
}

// ---------------------------------------------------------------------------
// Kernel 2: fused log-softmax + weighted NLL partial sum.
// Each thread handles 4 consecutive pixels (float4 per channel load).
// 512 blocks per sample: blockIdx>>9 = n (uniform per block).
// ---------------------------------------------------------------------------
__global__ __launch_bounds__(256) void loss_kernel(
    const float* __restrict__ x, const int* __restrict__ tgt,
    const int* __restrict__ hist, double* __restrict__ loss_sum) {
  __shared__ float lw[C_];
  const int tid = threadIdx.x;
  const int n = blockIdx.x >> 9;

  // Per-sample class weights: w[c] = sum_c' max(h,1) / max(h[c],1)   (RATIO=1)
  if (tid < C_) {
    int s = 0;
#pragma unroll
    for (int c = 0; c < C_; ++c) s += max(hist[n * C_ + c], 1);
    lw[tid] = (float)s / (float)max(hist[n * C_ + tid], 1);
  }
  __syncthreads();

  const int hw4 = ((blockIdx.x & 511) << 8) + tid;   // float4 index within sample
  const size_t hw = (size_t)hw4 * 4;

  // Load 19 channels x 4 pixels into registers (fully unrolled -> no scratch).
  const float4* xb =
      reinterpret_cast<const float4*>(x + ((size_t)n * C_) * HW_ + hw);
  const size_t cstride = HW_ / 4;   // float4 units

  float4 v[C_];
  float4 m = make_float4(-INFINITY, -INFINITY, -INFINITY, -INFINITY);
#pragma unroll
  for (int c = 0; c < C_; ++c) {
    v[c] = xb[(size_t)c * cstride];
    m.x = fmaxf(m.x, v[c].x);
    m.y = fmaxf(m.y, v[c].y);
    m.z = fmaxf(m.z, v[c].z);
    m.w = fmaxf(m.w, v[c].w);
  }

  // Targets for these 4 pixels.
  const int4 t4 = reinterpret_cast<const int4*>(tgt)[(size_t)n * cstride + hw4];
  const int t[4] = {t4.x, t4.y, t4.z, t4.w};
  bool valid[4];
  int tc[4];
#pragma unroll
  for (int j = 0; j < 4; ++j) {
    valid[j] = (t[j] != IGNORE_IDX);
    tc[j] = valid[j] ? min(max(t[j], 0), C_ - 1) : 0;
  }

  // One unrolled pass: sum exp(x-m) and predicated-select the target logit.
  float4 s = make_float4(0.f, 0.f, 0.f, 0.f);
  float xt0 = 0.f, xt1 = 0.f, xt2 = 0.f, xt3 = 0.f;
#pragma unroll
  for (int c = 0; c < C_; ++c) {
    s.x += expf(v[c].x - m.x);
    s.y += expf(v[c].y - m.y);
    s.z += expf(v[c].z - m.z);
    s.w += expf(v[c].w - m.w);
    xt0 = (c == tc[0]) ? v[c].x : xt0;
    xt1 = (c == tc[1]) ? v[c].y : xt1;
    xt2 = (c == tc[2]) ? v[c].z : xt2;
    xt3 = (c == tc[3]) ? v[c].w : xt3;
  }

  const float lse0 = m.x + logf(s.x);
  const float lse1 = m.y + logf(s.y);
  const float lse2 = m.z + logf(s.z);
  const float lse3 = m.w + logf(s.w);

  double acc = 0.0;
  acc += valid[0] ? (double)((lse0 - xt0) * lw[tc[0]]) : 0.0;
  acc += valid[1] ? (double)((lse1 - xt1) * lw[tc[1]]) : 0.0;
  acc += valid[2] ? (double)((lse2 - xt2) * lw[tc[2]]) : 0.0;
  acc += valid[3] ? (double)((lse3 - xt3) * lw[tc[3]]) : 0.0;

  // Wave reduce (64 lanes) then cross-wave via LDS, one atomic per block.
#pragma unroll
  for (int off = 32; off > 0; off >>= 1) acc += __shfl_down(acc, off, 64);
  __shared__ double wsum[4];
  const int wid = tid >> 6, lane = tid & 63;
  if (lane == 0) wsum[wid] = acc;
  __syncthreads();
  if (tid == 0) atomicAdd(loss_sum, wsum[0] + wsum[1] + wsum[2] + wsum[3]);
}

// ---------------------------------------------------------------------------
// Kernel 3: finalize
// ---------------------------------------------------------------------------
__global__ void finalize_kernel(const double* __restrict__ loss_sum,
                                const int* __restrict__ valid_cnt,
                                float* __restrict__ out) {
  if (threadIdx.x == 0 && blockIdx.x == 0) {
    const double denom = fmax((double)valid_cnt[0], 1.0);
    out[0] = (float)(loss_sum[0] / denom);
  }
}

extern "C" void kernel_launch(void* const* d_in, const int* in_sizes, int n_in,
                              void* d_out, int out_size, void* d_ws, size_t ws_size,
                              hipStream_t stream) {
  const float* inputs = (const float*)d_in[0];
  const int* targets = (const int*)d_in[1];
  float* out = (float*)d_out;

  int* hist = (int*)((char*)d_ws + WS_HIST_OFF);
  int* valid_cnt = (int*)((char*)d_ws + WS_VALID_OFF);
  double* loss_sum = (double*)((char*)d_ws + WS_LOSS_OFF);

  hipMemsetAsync(d_ws, 0, WS_ZERO_BYTES, stream);

  hist_kernel<<<1024, 256, 0, stream>>>(targets, hist, valid_cnt);

  // 4194304 pixels / 4 per thread / 256 per block = 4096 blocks (512/sample)
  loss_kernel<<<4096, 256, 0, stream>>>(inputs, targets, hist, loss_sum);

  finalize_kernel<<<1, 1, 0, stream>>>(loss_sum, valid_cnt, out);
}

// Round 8
// 469.090 us; speedup vs baseline: 1.0703x; 1.0703x over previous
//
#include <hip/hip_runtime.h>
#include <math.h>

#define N_  8
#define C_  19
#define H_  512
#define W_  1024
#define HW_ (H_ * W_)          // 524288
#define NPIX (N_ * HW_)        // 4194304
#define IGNORE_IDX 255

// Workspace layout (zeroed at start of every launch):
//   [0,   608)  int    hist[N_][C_]      (152 ints)
//   [608, 612)  int    valid_count
//   [616, 624)  double loss_sum
#define WS_HIST_OFF   0
#define WS_VALID_OFF  608
#define WS_LOSS_OFF   616
#define WS_ZERO_BYTES 1024

// ---------------------------------------------------------------------------
// Kernel 1: per-sample class histogram + valid count, ballot-popcount style.
// 512 blocks (64 per sample), 256 threads, 8 int4 per thread.
// Counting is wave-uniform (ballot -> SGPR popcount/add): no per-pixel LDS
// atomics, ~0.3 VALU ops per pixel.
// ---------------------------------------------------------------------------
__global__ __launch_bounds__(256) void hist_kernel(
    const int* __restrict__ tgt, int* __restrict__ hist, int* __restrict__ valid_cnt) {
  __shared__ int lh[C_];
  __shared__ int lvalid;
  const int tid = threadIdx.x;
  if (tid < C_) lh[tid] = 0;
  if (tid == 0) lvalid = 0;
  __syncthreads();

  const int n = blockIdx.x >> 6;     // 64 blocks per sample
  const int seg = blockIdx.x & 63;   // 2048 int4 per block
  const int4* tp = reinterpret_cast<const int4*>(tgt) +
                   (size_t)n * (HW_ / 4) + (size_t)seg * 2048;

  int cnt[C_];
#pragma unroll
  for (int c = 0; c < C_; ++c) cnt[c] = 0;
  int vcnt = 0;

#pragma unroll
  for (int it = 0; it < 8; ++it) {
    const int4 t4 = tp[it * 256 + tid];
    const int tv[4] = {t4.x, t4.y, t4.z, t4.w};
#pragma unroll
    for (int j = 0; j < 4; ++j) {
      vcnt += (int)__popcll(__ballot(tv[j] != IGNORE_IDX));
#pragma unroll
      for (int c = 0; c < C_; ++c)
        cnt[c] += (int)__popcll(__ballot(tv[j] == c));
    }
  }

  // cnt[] / vcnt are wave-uniform; wave leader merges into LDS, block leader
  // (threads 0..18) merges into global.
  if ((tid & 63) == 0) {
#pragma unroll
    for (int c = 0; c < C_; ++c)
      if (cnt[c]) atomicAdd(&lh[c], cnt[c]);
    atomicAdd(&lvalid, vcnt);
  }
  __syncthreads();
  if (tid < C_ && lh[tid]) atomicAdd(&hist[n * C_ + tid], lh[tid]);
  if (tid == 0 && lvalid) atomicAdd(valid_cnt, lvalid);
}

// ---------------------------------------------------------------------------
// Kernel 2: fused online log-softmax + weighted NLL partial sum.
// 2048 blocks (256 per sample), 256 threads, 8 pixels/thread as two float4
// streams (q0, q0+256). Online max/sum keeps VGPR use low (no v[19] array,
// no spill) while giving two independent dependency chains for ILP.
// __expf/__logf = native v_exp/v_log (~3 ops) instead of OCML libm (~20).
// ---------------------------------------------------------------------------
__global__ __launch_bounds__(256) void loss_kernel(
    const float* __restrict__ x, const int* __restrict__ tgt,
    const int* __restrict__ hist, double* __restrict__ loss_sum) {
  __shared__ float lw[C_];
  const int tid = threadIdx.x;
  const int n = blockIdx.x >> 8;   // 256 blocks per sample

  // Per-sample class weights: w[c] = sum_c' max(h,1) / max(h[c],1)  (RATIO=1)
  if (tid < C_) {
    int s = 0;
#pragma unroll
    for (int c = 0; c < C_; ++c) s += max(hist[n * C_ + c], 1);
    lw[tid] = (float)s / (float)max(hist[n * C_ + tid], 1);
  }
  __syncthreads();

  const int blk = blockIdx.x & 255;       // block's slice within sample
  const int q0 = blk * 512 + tid;         // float4 index within sample
  const int q1 = q0 + 256;
  const float* xb = x + (size_t)n * C_ * HW_;

  // Targets for the 8 pixels.
  const int4* tq = reinterpret_cast<const int4*>(tgt + (size_t)n * HW_);
  const int4 ta = tq[q0];
  const int4 tb = tq[q1];
  const int t[8] = {ta.x, ta.y, ta.z, ta.w, tb.x, tb.y, tb.z, tb.w};
  bool val[8];
  int tc[8];
#pragma unroll
  for (int j = 0; j < 8; ++j) {
    val[j] = (t[j] != IGNORE_IDX);
    tc[j] = val[j] ? min(max(t[j], 0), C_ - 1) : 0;
  }

  float m[8], s[8], xt[8];
#pragma unroll
  for (int j = 0; j < 8; ++j) {
    m[j] = -INFINITY;
    s[j] = 0.f;
    xt[j] = 0.f;
  }

#pragma unroll
  for (int c = 0; c < C_; ++c) {
    const float4* xc = reinterpret_cast<const float4*>(xb + (size_t)c * HW_);
    const float4 va = xc[q0];
    const float4 vb = xc[q1];
    const float v[8] = {va.x, va.y, va.z, va.w, vb.x, vb.y, vb.z, vb.w};
#pragma unroll
    for (int j = 0; j < 8; ++j) {
      const float nm = fmaxf(m[j], v[j]);
      s[j] = s[j] * __expf(m[j] - nm) + __expf(v[j] - nm);
      m[j] = nm;
      xt[j] = (c == tc[j]) ? v[j] : xt[j];
    }
  }

  double acc = 0.0;
#pragma unroll
  for (int j = 0; j < 8; ++j) {
    const float lse = m[j] + __logf(s[j]);
    acc += val[j] ? (double)((lse - xt[j]) * lw[tc[j]]) : 0.0;
  }

  // Wave reduce (64 lanes) then cross-wave via LDS, one double atomic/block.
#pragma unroll
  for (int off = 32; off > 0; off >>= 1) acc += __shfl_down(acc, off, 64);
  __shared__ double wsum[4];
  const int wid = tid >> 6, lane = tid & 63;
  if (lane == 0) wsum[wid] = acc;
  __syncthreads();
  if (tid == 0) atomicAdd(loss_sum, wsum[0] + wsum[1] + wsum[2] + wsum[3]);
}

// ---------------------------------------------------------------------------
// Kernel 3: finalize
// ---------------------------------------------------------------------------
__global__ void finalize_kernel(const double* __restrict__ loss_sum,
                                const int* __restrict__ valid_cnt,
                                float* __restrict__ out) {
  if (threadIdx.x == 0 && blockIdx.x == 0) {
    const double denom = fmax((double)valid_cnt[0], 1.0);
    out[0] = (float)(loss_sum[0] / denom);
  }
}

extern "C" void kernel_launch(void* const* d_in, const int* in_sizes, int n_in,
                              void* d_out, int out_size, void* d_ws, size_t ws_size,
                              hipStream_t stream) {
  const float* inputs = (const float*)d_in[0];
  const int* targets = (const int*)d_in[1];
  float* out = (float*)d_out;

  int* hist = (int*)((char*)d_ws + WS_HIST_OFF);
  int* valid_cnt = (int*)((char*)d_ws + WS_VALID_OFF);
  double* loss_sum = (double*)((char*)d_ws + WS_LOSS_OFF);

  hipMemsetAsync(d_ws, 0, WS_ZERO_BYTES, stream);

  hist_kernel<<<512, 256, 0, stream>>>(targets, hist, valid_cnt);

  // 4194304 pixels / 8 per thread / 256 per block = 2048 blocks (256/sample)
  loss_kernel<<<2048, 256, 0, stream>>>(inputs, targets, hist, loss_sum);

  finalize_kernel<<<1, 1, 0, stream>>>(loss_sum, valid_cnt, out);
}

// Round 12
// 452.979 us; speedup vs baseline: 1.1084x; 1.0356x over previous
//
#include <hip/hip_runtime.h>
#include <math.h>

#define N_  8
#define C_  19
#define H_  512
#define W_  1024
#define HW_ (H_ * W_)          // 524288
#define NPIX (N_ * HW_)        // 4194304
#define IGNORE_IDX 255
#define LOSS_BLOCKS 2048

// Workspace layout:
//   [0,    608)  int    hist[N_][C_]      (152 ints)   -- zeroed
//   [608,  612)  int    valid_count                    -- zeroed
//   [1024, 17408) double part[LOSS_BLOCKS]             -- fully written by loss_kernel
#define WS_HIST_OFF   0
#define WS_VALID_OFF  608
#define WS_PART_OFF   1024
#define WS_ZERO_BYTES 1024

// ---------------------------------------------------------------------------
// Kernel 1: per-sample class histogram + valid count, ballot-popcount style.
// 512 blocks (64 per sample), 256 threads, 8 int4 per thread.
// Counting is wave-uniform (ballot -> SGPR popcount/add): no per-pixel LDS
// atomics, ~0.3 VALU ops per pixel.
// ---------------------------------------------------------------------------
__global__ __launch_bounds__(256) void hist_kernel(
    const int* __restrict__ tgt, int* __restrict__ hist, int* __restrict__ valid_cnt) {
  __shared__ int lh[C_];
  __shared__ int lvalid;
  const int tid = threadIdx.x;
  if (tid < C_) lh[tid] = 0;
  if (tid == 0) lvalid = 0;
  __syncthreads();

  const int n = blockIdx.x >> 6;     // 64 blocks per sample
  const int seg = blockIdx.x & 63;   // 2048 int4 per block
  const int4* tp = reinterpret_cast<const int4*>(tgt) +
                   (size_t)n * (HW_ / 4) + (size_t)seg * 2048;

  int cnt[C_];
#pragma unroll
  for (int c = 0; c < C_; ++c) cnt[c] = 0;
  int vcnt = 0;

#pragma unroll
  for (int it = 0; it < 8; ++it) {
    const int4 t4 = tp[it * 256 + tid];
    const int tv[4] = {t4.x, t4.y, t4.z, t4.w};
#pragma unroll
    for (int j = 0; j < 4; ++j) {
      vcnt += (int)__popcll(__ballot(tv[j] != IGNORE_IDX));
#pragma unroll
      for (int c = 0; c < C_; ++c)
        cnt[c] += (int)__popcll(__ballot(tv[j] == c));
    }
  }

  // cnt[] / vcnt are wave-uniform; wave leader merges into LDS, block leader
  // (threads 0..18) merges into global.
  if ((tid & 63) == 0) {
#pragma unroll
    for (int c = 0; c < C_; ++c)
      if (cnt[c]) atomicAdd(&lh[c], cnt[c]);
    atomicAdd(&lvalid, vcnt);
  }
  __syncthreads();
  if (tid < C_ && lh[tid]) atomicAdd(&hist[n * C_ + tid], lh[tid]);
  if (tid == 0 && lvalid) atomicAdd(valid_cnt, lvalid);
}

// ---------------------------------------------------------------------------
// Kernel 2: fused online log-softmax + weighted NLL partial sum.
// 2048 blocks (256 per sample), 256 threads, 8 pixels/thread as two float4
// streams (q0, q0+256). Online max/sum keeps VGPR use low; __expf/__logf are
// native v_exp/v_log. Block partial goes to part[blockIdx.x] (NO same-address
// f64 atomic: 2048 serialized cross-XCD atomics suspected as a 20-100 us tail).
// ---------------------------------------------------------------------------
__global__ __launch_bounds__(256) void loss_kernel(
    const float* __restrict__ x, const int* __restrict__ tgt,
    const int* __restrict__ hist, double* __restrict__ part) {
  __shared__ float lw[C_];
  const int tid = threadIdx.x;
  const int n = blockIdx.x >> 8;   // 256 blocks per sample

  // Per-sample class weights: w[c] = sum_c' max(h,1) / max(h[c],1)  (RATIO=1)
  if (tid < C_) {
    int s = 0;
#pragma unroll
    for (int c = 0; c < C_; ++c) s += max(hist[n * C_ + c], 1);
    lw[tid] = (float)s / (float)max(hist[n * C_ + tid], 1);
  }
  __syncthreads();

  const int blk = blockIdx.x & 255;       // block's slice within sample
  const int q0 = blk * 512 + tid;         // float4 index within sample
  const int q1 = q0 + 256;
  const float* xb = x + (size_t)n * C_ * HW_;

  // Targets for the 8 pixels.
  const int4* tq = reinterpret_cast<const int4*>(tgt + (size_t)n * HW_);
  const int4 ta = tq[q0];
  const int4 tb = tq[q1];
  const int t[8] = {ta.x, ta.y, ta.z, ta.w, tb.x, tb.y, tb.z, tb.w};
  bool val[8];
  int tc[8];
#pragma unroll
  for (int j = 0; j < 8; ++j) {
    val[j] = (t[j] != IGNORE_IDX);
    tc[j] = val[j] ? min(max(t[j], 0), C_ - 1) : 0;
  }

  float m[8], s[8], xt[8];
#pragma unroll
  for (int j = 0; j < 8; ++j) {
    m[j] = -INFINITY;
    s[j] = 0.f;
    xt[j] = 0.f;
  }

#pragma unroll
  for (int c = 0; c < C_; ++c) {
    const float4* xc = reinterpret_cast<const float4*>(xb + (size_t)c * HW_);
    const float4 va = xc[q0];
    const float4 vb = xc[q1];
    const float v[8] = {va.x, va.y, va.z, va.w, vb.x, vb.y, vb.z, vb.w};
#pragma unroll
    for (int j = 0; j < 8; ++j) {
      const float nm = fmaxf(m[j], v[j]);
      s[j] = s[j] * __expf(m[j] - nm) + __expf(v[j] - nm);
      m[j] = nm;
      xt[j] = (c == tc[j]) ? v[j] : xt[j];
    }
  }

  double acc = 0.0;
#pragma unroll
  for (int j = 0; j < 8; ++j) {
    const float lse = m[j] + __logf(s[j]);
    acc += val[j] ? (double)((lse - xt[j]) * lw[tc[j]]) : 0.0;
  }

  // Wave reduce (64 lanes) then cross-wave via LDS; block leader writes its
  // private partial slot (no global atomic).
#pragma unroll
  for (int off = 32; off > 0; off >>= 1) acc += __shfl_down(acc, off, 64);
  __shared__ double wsum[4];
  const int wid = tid >> 6, lane = tid & 63;
  if (lane == 0) wsum[wid] = acc;
  __syncthreads();
  if (tid == 0) part[blockIdx.x] = wsum[0] + wsum[1] + wsum[2] + wsum[3];
}

// ---------------------------------------------------------------------------
// Kernel 3: reduce 2048 block partials + finalize (1 block, 256 threads).
// ---------------------------------------------------------------------------
__global__ __launch_bounds__(256) void finalize_kernel(
    const double* __restrict__ part, const int* __restrict__ valid_cnt,
    float* __restrict__ out) {
  const int tid = threadIdx.x;
  double a = 0.0;
#pragma unroll
  for (int i = 0; i < LOSS_BLOCKS / 256; ++i) a += part[i * 256 + tid];
#pragma unroll
  for (int off = 32; off > 0; off >>= 1) a += __shfl_down(a, off, 64);
  __shared__ double ws[4];
  const int wid = tid >> 6, lane = tid & 63;
  if (lane == 0) ws[wid] = a;
  __syncthreads();
  if (tid == 0) {
    const double s = ws[0] + ws[1] + ws[2] + ws[3];
    const double denom = fmax((double)valid_cnt[0], 1.0);
    out[0] = (float)(s / denom);
  }
}

extern "C" void kernel_launch(void* const* d_in, const int* in_sizes, int n_in,
                              void* d_out, int out_size, void* d_ws, size_t ws_size,
                              hipStream_t stream) {
  const float* inputs = (const float*)d_in[0];
  const int* targets = (const int*)d_in[1];
  float* out = (float*)d_out;

  int* hist = (int*)((char*)d_ws + WS_HIST_OFF);
  int* valid_cnt = (int*)((char*)d_ws + WS_VALID_OFF);
  double* part = (double*)((char*)d_ws + WS_PART_OFF);

  hipMemsetAsync(d_ws, 0, WS_ZERO_BYTES, stream);

  hist_kernel<<<512, 256, 0, stream>>>(targets, hist, valid_cnt);

  // 4194304 pixels / 8 per thread / 256 per block = 2048 blocks (256/sample)
  loss_kernel<<<LOSS_BLOCKS, 256, 0, stream>>>(inputs, targets, hist, part);

  finalize_kernel<<<1, 256, 0, stream>>>(part, valid_cnt, out);
}